// Round 6
// baseline (1089.057 us; speedup 1.0000x reference)
//
#include <hip/hip_runtime.h>
#include <math.h>

#define S     64
#define NSUB  1024
#define ESUB  16384
#define NG    65536
#define EG    1048576
#define NH    128
#define KSEL  512
#define NBUCK 512          // global-CSR fill buckets: 128 nodes each

// ---------------- CSR build (per-subgraph) ----------------
__global__ void k_count_sub(const int* __restrict__ sei, int* __restrict__ cnt) {
    int e = blockIdx.x * 256 + threadIdx.x;          // < S*ESUB
    int s = e >> 14, el = e & (ESUB - 1);
    int dst = sei[s * 2 * ESUB + ESUB + el];
    atomicAdd(&cnt[s * NSUB + dst], 1);
}

__global__ __launch_bounds__(1024) void k_scan_sub(const int* __restrict__ cnt,
        int* __restrict__ rowptr, int* __restrict__ cur, float* __restrict__ dinv) {
    __shared__ int sh[1024];
    int s = blockIdx.x, t = threadIdx.x;
    int v = cnt[s * NSUB + t];
    sh[t] = v;
    __syncthreads();
    for (int off = 1; off < 1024; off <<= 1) {
        int add = (t >= off) ? sh[t - off] : 0;
        __syncthreads();
        sh[t] += add;
        __syncthreads();
    }
    int incl = sh[t];
    rowptr[s * (NSUB + 1) + t] = incl - v;
    cur[s * NSUB + t] = incl - v;
    dinv[s * NSUB + t] = rsqrtf((float)(v + 1));     // deg = indeg + 1 (self loop)
    if (t == 1023) rowptr[s * (NSUB + 1) + NSUB] = incl;
}

__global__ void k_fill_sub(const int* __restrict__ sei, int* __restrict__ cur,
                           int* __restrict__ col) {
    int e = blockIdx.x * 256 + threadIdx.x;
    int s = e >> 14, el = e & (ESUB - 1);
    int src = sei[s * 2 * ESUB + el];
    int dst = sei[s * 2 * ESUB + ESUB + el];
    int p = atomicAdd(&cur[s * NSUB + dst], 1);
    col[s * ESUB + p] = src;
}

// ---------------- tiled matmul: Y[M,NCOL] = X[M,KDIM] @ W[KDIM,NCOL] (all f32) --------
template<int KDIM, int NCOL>
__global__ __launch_bounds__(256) void k_matmul(const float* __restrict__ X,
        const float* __restrict__ W, float* __restrict__ Y) {
    __shared__ float As[16][72];
    __shared__ float Bs[16][72];
    int t = threadIdx.x;
    int row0 = blockIdx.x * 64;
    int col0 = blockIdx.y * 64;
    int tr = t >> 4, tc = t & 15;
    float acc[4][4] = {};
    for (int k0 = 0; k0 < KDIM; k0 += 16) {
        {   // stage A: 64 rows x 16 k
            int r = t >> 2, kq = t & 3;
            float4 v = *(const float4*)&X[(size_t)(row0 + r) * KDIM + k0 + kq * 4];
            As[kq * 4 + 0][r] = v.x; As[kq * 4 + 1][r] = v.y;
            As[kq * 4 + 2][r] = v.z; As[kq * 4 + 3][r] = v.w;
        }
        {   // stage B
            int k = t >> 4, cq = t & 15;
            float4 v = *(const float4*)&W[(size_t)(k0 + k) * NCOL + col0 + cq * 4];
            *(float4*)&Bs[k][cq * 4] = v;
        }
        __syncthreads();
        #pragma unroll
        for (int k = 0; k < 16; k++) {
            float a0 = As[k][tr * 4 + 0], a1 = As[k][tr * 4 + 1];
            float a2 = As[k][tr * 4 + 2], a3 = As[k][tr * 4 + 3];
            float b0 = Bs[k][tc * 4 + 0], b1 = Bs[k][tc * 4 + 1];
            float b2 = Bs[k][tc * 4 + 2], b3 = Bs[k][tc * 4 + 3];
            acc[0][0] += a0 * b0; acc[0][1] += a0 * b1; acc[0][2] += a0 * b2; acc[0][3] += a0 * b3;
            acc[1][0] += a1 * b0; acc[1][1] += a1 * b1; acc[1][2] += a1 * b2; acc[1][3] += a1 * b3;
            acc[2][0] += a2 * b0; acc[2][1] += a2 * b1; acc[2][2] += a2 * b2; acc[2][3] += a2 * b3;
            acc[3][0] += a3 * b0; acc[3][1] += a3 * b1; acc[3][2] += a3 * b2; acc[3][3] += a3 * b3;
        }
        __syncthreads();
    }
    #pragma unroll
    for (int i = 0; i < 4; i++) {
        float4 v = { acc[i][0], acc[i][1], acc[i][2], acc[i][3] };
        *(float4*)&Y[(size_t)(row0 + tr * 4 + i) * NCOL + col0 + tc * 4] = v;
    }
}

// ------- GCN aggregate (128 feats) + self + bias + relu; float4 + XCD swizzle --------
__global__ __launch_bounds__(256) void k_agg128(const float4* __restrict__ h,
        const float* __restrict__ dinv, const int* __restrict__ rowptr,
        const int* __restrict__ col, const float* __restrict__ bias,
        float4* __restrict__ out) {
    int b = blockIdx.x;
    int s = b & 63;                      // subgraph -> fixed XCD (b%8 == s%8)
    int chunk = b >> 6;
    int t = threadIdx.x;
    int nl = chunk * 8 + (t >> 5);
    int f4 = t & 31;
    const int* rp = rowptr + s * (NSUB + 1);
    int st = rp[nl], en = rp[nl + 1];
    const int* cl = col + s * ESUB;
    const float* dv = dinv + s * NSUB;
    float4 acc = {0.f, 0.f, 0.f, 0.f};
    for (int p = st; p < en; p++) {
        int src = cl[p];
        float d = dv[src];
        float4 hv = h[((size_t)(s * NSUB + src)) * 32 + f4];
        acc.x += hv.x * d; acc.y += hv.y * d; acc.z += hv.z * d; acc.w += hv.w * d;
    }
    size_t node = (size_t)s * NSUB + nl;
    float dn = dv[nl];
    float dn2 = dn * dn;
    float4 hs = h[node * 32 + f4];
    float4 bb = ((const float4*)bias)[f4];
    float4 r;
    r.x = fmaxf(acc.x * dn + hs.x * dn2 + bb.x, 0.f);
    r.y = fmaxf(acc.y * dn + hs.y * dn2 + bb.y, 0.f);
    r.z = fmaxf(acc.z * dn + hs.z * dn2 + bb.z, 0.f);
    r.w = fmaxf(acc.w * dn + hs.w * dn2 + bb.w, 0.f);
    out[node * 32 + f4] = r;
}

// ---------------- scorer ----------------
__global__ void k_score_h(const float* __restrict__ x1, const float* __restrict__ Wp,
                          float* __restrict__ sh) {
    int t = threadIdx.x;
    int n = blockIdx.x * 4 + (t >> 6);
    int l = t & 63;
    float p = x1[(size_t)n * NH + l] * Wp[l] + x1[(size_t)n * NH + 64 + l] * Wp[64 + l];
    for (int o = 32; o > 0; o >>= 1) p += __shfl_xor(p, o, 64);
    if (l == 0) sh[n] = p;
}

__global__ void k_score_agg(const float* __restrict__ sh, const float* __restrict__ dinv,
                            const int* __restrict__ rowptr, const int* __restrict__ col,
                            const float* __restrict__ bp, float* __restrict__ score) {
    int n = blockIdx.x * 256 + threadIdx.x;
    int s = n >> 10, nl = n & (NSUB - 1);
    const int* rp = rowptr + s * (NSUB + 1);
    const int* cl = col + s * ESUB;
    const float* dv = dinv + s * NSUB;
    int st = rp[nl], en = rp[nl + 1];
    float acc = 0.f;
    for (int p = st; p < en; p++) {
        int src = cl[p];
        acc += sh[s * NSUB + src] * dv[src];
    }
    float dn = dv[nl];
    score[n] = acc * dn + sh[n] * dn * dn + bp[0];
}

// ---------------- per-subgraph top-K (bitonic; set-invariant downstream) -----
__global__ __launch_bounds__(512) void k_topk(const float* __restrict__ score,
        int* __restrict__ perm, float* __restrict__ gate, int* __restrict__ posmap) {
    __shared__ float sv[1024];
    __shared__ int   si[1024];
    int s = blockIdx.x, t = threadIdx.x;
    for (int i = t; i < 1024; i += 512) {
        sv[i] = score[s * NSUB + i];
        si[i] = i;
        posmap[s * NSUB + i] = -1;
    }
    __syncthreads();
    for (int k = 2; k <= 1024; k <<= 1) {
        for (int j = k >> 1; j > 0; j >>= 1) {
            for (int b = t; b < 1024; b += 512) {
                int ixj = b ^ j;
                if (ixj > b) {
                    bool desc = ((b & k) == 0);
                    bool sw = desc ? (sv[b] < sv[ixj]) : (sv[b] > sv[ixj]);
                    if (sw) {
                        float tv = sv[b]; sv[b] = sv[ixj]; sv[ixj] = tv;
                        int ti = si[b]; si[b] = si[ixj]; si[ixj] = ti;
                    }
                }
            }
            __syncthreads();
        }
    }
    if (t < KSEL) {
        perm[s * KSEL + t] = si[t];
        gate[s * KSEL + t] = tanhf(sv[t]);
        posmap[s * NSUB + si[t]] = t;
    }
}

__global__ void k_deg2(const int* __restrict__ perm, const int* __restrict__ posmap,
                       const int* __restrict__ rowptr, const int* __restrict__ col,
                       float* __restrict__ dinv2) {
    int i = blockIdx.x * 256 + threadIdx.x;
    int s = i >> 9;
    int n = perm[i];
    const int* rp = rowptr + s * (NSUB + 1);
    const int* cl = col + s * ESUB;
    int st = rp[n], en = rp[n + 1];
    int cnt = 0;
    for (int p = st; p < en; p++) cnt += (posmap[s * NSUB + cl[p]] >= 0) ? 1 : 0;
    dinv2[i] = rsqrtf((float)(cnt + 1));
}

__global__ void k_xpool(const float4* __restrict__ x1, const int* __restrict__ perm,
                        const float* __restrict__ gate, float4* __restrict__ xpool) {
    int tid = blockIdx.x * 256 + threadIdx.x;
    int i = tid >> 5, f4 = tid & 31;
    int s = i >> 9;
    float g = gate[i];
    float4 v = x1[((size_t)(s * NSUB + perm[i])) * 32 + f4];
    v.x *= g; v.y *= g; v.z *= g; v.w *= g;
    xpool[tid] = v;
}

// max/mean over 512 rows -> [256] per subgraph; 4-sliced
__global__ __launch_bounds__(1024) void k_emb(const float* __restrict__ X,
        float* __restrict__ out, int addFlag) {
    __shared__ float red[4][256];
    int s = blockIdx.x, t = threadIdx.x;
    int sl = t >> 8, f = t & 255;
    const float* base = X + (size_t)s * KSEL * NH;
    float r;
    if (f < NH) {
        r = -INFINITY;
        for (int i = sl * 128; i < sl * 128 + 128; i++) r = fmaxf(r, base[i * NH + f]);
    } else {
        r = 0.f;
        for (int i = sl * 128; i < sl * 128 + 128; i++) r += base[i * NH + (f - NH)];
    }
    red[sl][f] = r;
    __syncthreads();
    if (sl == 0) {
        float a = red[0][f], b = red[1][f], c = red[2][f], d = red[3][f];
        float v = (f < NH) ? fmaxf(fmaxf(a, b), fmaxf(c, d)) : (a + b + c + d) * (1.f / KSEL);
        out[s * 256 + f] = addFlag ? out[s * 256 + f] + v : v;
    }
}

// pooled GCN aggregate; float4 + XCD swizzle
__global__ __launch_bounds__(256) void k_agg_pool(const float4* __restrict__ hp,
        const float* __restrict__ dinv2, const int* __restrict__ perm,
        const int* __restrict__ posmap, const int* __restrict__ rowptr,
        const int* __restrict__ col, const float* __restrict__ bsc,
        float4* __restrict__ xsub) {
    int b = blockIdx.x;
    int s = b & 63;
    int chunk = b >> 6;
    int t = threadIdx.x;
    int il = chunk * 8 + (t >> 5);
    int f4 = t & 31;
    int i = s * KSEL + il;
    int n = perm[i];
    const int* rp = rowptr + s * (NSUB + 1);
    const int* cl = col + s * ESUB;
    int st = rp[n], en = rp[n + 1];
    float4 acc = {0.f, 0.f, 0.f, 0.f};
    for (int p = st; p < en; p++) {
        int j = posmap[s * NSUB + cl[p]];
        if (j >= 0) {
            float d = dinv2[s * KSEL + j];
            float4 hv = hp[((size_t)(s * KSEL + j)) * 32 + f4];
            acc.x += hv.x * d; acc.y += hv.y * d; acc.z += hv.z * d; acc.w += hv.w * d;
        }
    }
    float dn = dinv2[i];
    float dn2 = dn * dn;
    float4 hs = hp[(size_t)i * 32 + f4];
    float4 bb = ((const float4*)bsc)[f4];
    float4 r;
    r.x = fmaxf(acc.x * dn + hs.x * dn2 + bb.x, 0.f);
    r.y = fmaxf(acc.y * dn + hs.y * dn2 + bb.y, 0.f);
    r.z = fmaxf(acc.z * dn + hs.z * dn2 + bb.z, 0.f);
    r.w = fmaxf(acc.w * dn + hs.w * dn2 + bb.w, 0.f);
    xsub[(size_t)i * 32 + f4] = r;
}

// attention degenerates (seq_len=1): att = (se@Wv + bv)@Wo + bo
__global__ void k_attn(const float* __restrict__ subemb, const float* __restrict__ Wqkv,
                       const float* __restrict__ bqkv, const float* __restrict__ Wo,
                       const float* __restrict__ bo, float* __restrict__ att) {
    __shared__ float se[256], t1[256];
    int s = blockIdx.x, t = threadIdx.x;
    se[t] = subemb[s * 256 + t];
    __syncthreads();
    float acc = bqkv[512 + t];
    for (int k = 0; k < 256; k++) acc += se[k] * Wqkv[(size_t)k * 768 + 512 + t];
    t1[t] = acc;
    __syncthreads();
    float a2 = bo[t];
    for (int k = 0; k < 256; k++) a2 += t1[k] * Wo[(size_t)k * 256 + t];
    att[s * 256 + t] = a2;
}

// ---------------- generic counting-scan helpers (64x1024 = NG entries) --------
__global__ void k_countR(const int* __restrict__ orig, int* __restrict__ cnt) {
    int r = blockIdx.x * 256 + threadIdx.x;          // < NG
    atomicAdd(&cnt[orig[r]], 1);
}

__global__ __launch_bounds__(1024) void k_scanN_p1(const int* __restrict__ cnt,
        int* __restrict__ rowptr, float* __restrict__ dinvN, int* __restrict__ bsum) {
    __shared__ int sh[1024];
    int b = blockIdx.x, t = threadIdx.x;
    int v = cnt[b * 1024 + t];
    sh[t] = v;
    __syncthreads();
    for (int off = 1; off < 1024; off <<= 1) {
        int add = (t >= off) ? sh[t - off] : 0;
        __syncthreads();
        sh[t] += add;
        __syncthreads();
    }
    int incl = sh[t];
    rowptr[b * 1024 + t] = incl - v;
    dinvN[b * 1024 + t] = rsqrtf((float)(v + 1));
    if (t == 1023) bsum[b] = incl;
}

__global__ void k_scanN_p2(const int* __restrict__ bsum, int* __restrict__ boff) {
    if (threadIdx.x == 0) {
        int run = 0;
        for (int i = 0; i < 64; i++) { boff[i] = run; run += bsum[i]; }
    }
}

__global__ __launch_bounds__(1024) void k_scanN_p3(int* __restrict__ rowptr,
        int* __restrict__ cur, const int* __restrict__ boff, int total) {
    int b = blockIdx.x, t = threadIdx.x;
    int idx = b * 1024 + t;
    int r = rowptr[idx] + boff[b];
    rowptr[idx] = r;
    cur[idx] = r;
    if (idx == 0) rowptr[NG] = total;
}

__global__ void k_fillR(const int* __restrict__ orig, int* __restrict__ cur,
                        int* __restrict__ rowlist) {
    int r = blockIdx.x * 256 + threadIdx.x;          // < NG
    int p = atomicAdd(&cur[orig[r]], 1);
    rowlist[p] = r;
}

// gather-based global_emb build: one gemb row written once, no atomics, no memset
__global__ __launch_bounds__(384) void k_gather(const float4* __restrict__ x2,
        const float4* __restrict__ att, const int* __restrict__ rowptrR,
        const int* __restrict__ rowlist, float4* __restrict__ gemb) {
    int t = threadIdx.x;
    int g = blockIdx.x * 4 + (t / 96);               // 4 nodes / block
    int lane = t % 96;                               // 96 float4 = 384 feats
    int st = rowptrR[g], en = rowptrR[g + 1];
    float4 acc = {0.f, 0.f, 0.f, 0.f};
    for (int p = st; p < en; p++) {
        int row = rowlist[p];
        float4 v = (lane < 32) ? x2[(size_t)row * 32 + lane]
                               : att[(size_t)(row >> 10) * 64 + (lane - 32)];
        acc.x += v.x; acc.y += v.y; acc.z += v.z; acc.w += v.w;
    }
    gemb[(size_t)g * 96 + lane] = acc;
}

// ---------------- global edge CSR: count + bucketed fill ----------------
__global__ void k_countN(const int* __restrict__ gei, int* __restrict__ cnt) {
    int e = blockIdx.x * 256 + threadIdx.x;
    atomicAdd(&cnt[gei[EG + e]], 1);
}

__global__ void k_binit(const int* __restrict__ rowptrN, int* __restrict__ bcur) {
    int i = blockIdx.x * 256 + threadIdx.x;
    if (i < NBUCK) bcur[i] = rowptrN[i * 128];
}

__global__ void k_bucket(const int* __restrict__ gei, int* __restrict__ bcur,
                         int2* __restrict__ ebuck) {
    int e = blockIdx.x * 256 + threadIdx.x;
    int src = gei[e], dst = gei[EG + e];
    int p = atomicAdd(&bcur[dst >> 7], 1);           // dense slots -> full-line writes
    ebuck[p] = make_int2(src, dst);
}

__global__ __launch_bounds__(256) void k_fillB(const int2* __restrict__ ebuck,
        const int* __restrict__ rowptrN, int* __restrict__ col) {
    __shared__ int cur[128];
    int b = blockIdx.x;                              // 512 buckets of 128 nodes
    int t = threadIdx.x;
    if (t < 128) cur[t] = rowptrN[b * 128 + t];
    __syncthreads();
    int base = rowptrN[b * 128];
    int end  = rowptrN[(b + 1) * 128];               // b=511 hits rowptrN[NG]=EG
    for (int p = base + t; p < end; p += 256) {
        int2 e = ebuck[p];
        int pos = atomicAdd(&cur[e.y & 127], 1);     // LDS cursor
        col[pos] = e.x;                              // contiguous ~8KB window per block
    }
}

// final GCN aggregate + bias + log_softmax (64 classes = 16 float4 lanes)
__global__ __launch_bounds__(256) void k_final(const float4* __restrict__ hf,
        const float* __restrict__ dinvN, const int* __restrict__ rowptr,
        const int* __restrict__ col, const float* __restrict__ bfb,
        float4* __restrict__ out) {
    int t = threadIdx.x;
    int n = blockIdx.x * 16 + (t >> 4);
    int f4 = t & 15;
    int st = rowptr[n], en = rowptr[n + 1];
    float4 acc = {0.f, 0.f, 0.f, 0.f};
    for (int p = st; p < en; p++) {
        int src = col[p];
        float d = dinvN[src];
        float4 hv = hf[(size_t)src * 16 + f4];
        acc.x += hv.x * d; acc.y += hv.y * d; acc.z += hv.z * d; acc.w += hv.w * d;
    }
    float dn = dinvN[n];
    float dn2 = dn * dn;
    float4 hs = hf[(size_t)n * 16 + f4];
    float4 bb = ((const float4*)bfb)[f4];
    float4 x;
    x.x = acc.x * dn + hs.x * dn2 + bb.x;
    x.y = acc.y * dn + hs.y * dn2 + bb.y;
    x.z = acc.z * dn + hs.z * dn2 + bb.z;
    x.w = acc.w * dn + hs.w * dn2 + bb.w;
    float m = fmaxf(fmaxf(x.x, x.y), fmaxf(x.z, x.w));
    for (int o = 1; o < 16; o <<= 1) m = fmaxf(m, __shfl_xor(m, o, 64));
    float ssum = expf(x.x - m) + expf(x.y - m) + expf(x.z - m) + expf(x.w - m);
    for (int o = 1; o < 16; o <<= 1) ssum += __shfl_xor(ssum, o, 64);
    float lz = m + logf(ssum);
    float4 r = { x.x - lz, x.y - lz, x.z - lz, x.w - lz };
    out[(size_t)n * 16 + f4] = r;
}

// ---------------- host ----------------
extern "C" void kernel_launch(void* const* d_in, const int* in_sizes, int n_in,
                              void* d_out, int out_size, void* d_ws, size_t ws_size,
                              hipStream_t stream) {
    const float* sub_x = (const float*)d_in[0];
    const int*   sei   = (const int*)d_in[1];
    const int*   sorig = (const int*)d_in[2];
    const int*   gei   = (const int*)d_in[3];
    const float *W1 = (const float*)d_in[4],  *b1  = (const float*)d_in[5];
    const float *W2 = (const float*)d_in[6],  *b2  = (const float*)d_in[7];
    const float *Wp = (const float*)d_in[8],  *bp  = (const float*)d_in[9];
    const float *Wsc = (const float*)d_in[10], *bsc = (const float*)d_in[11];
    const float *Wqkv = (const float*)d_in[12], *bqkv = (const float*)d_in[13];
    const float *Wo = (const float*)d_in[14], *bo  = (const float*)d_in[15];
    const float *Wf = (const float*)d_in[16], *bfb = (const float*)d_in[17];

    float* out0 = (float*)d_out;                      // log-softmax [NG,64]
    float* gemb = (float*)d_out + (size_t)NG * 64;    // global_emb [NG,384] in-place

    char* w = (char*)d_ws;
    size_t off = 0;
    auto alloc = [&](size_t nbytes) -> void* {
        off = (off + 255) & ~(size_t)255;
        void* p = w + off;
        off += nbytes;
        return p;
    };
    int*   bsum    = (int*)alloc(64 * 4);
    int*   boff    = (int*)alloc(64 * 4);
    int*   bcur    = (int*)alloc(NBUCK * 4);
    float* dinv    = (float*)alloc((size_t)NG * 4);        // subgraph dinv; later dinvN + scan scratch
    float* scoreh  = (float*)alloc((size_t)NG * 4);
    float* score   = (float*)alloc((size_t)NG * 4);
    float* gate    = (float*)alloc((size_t)S * KSEL * 4);
    float* dinv2   = (float*)alloc((size_t)S * KSEL * 4);
    float* subemb  = (float*)alloc((size_t)S * 256 * 4);
    float* att     = (float*)alloc((size_t)S * 256 * 4);
    int*   perm    = (int*)alloc((size_t)S * KSEL * 4);
    int*   posmap  = (int*)alloc((size_t)NG * 4);
    int*   cnt_sub = (int*)alloc((size_t)NG * 4);          // alias: cntN
    int*   cur_sub = (int*)alloc((size_t)NG * 4);          // alias: curN/curR
    int*   rowptr_s= (int*)alloc((size_t)(NG + 64) * 4);   // alias: rowptrN
    int*   col_sub = (int*)alloc((size_t)EG * 4);          // alias: colN
    int*   rowptrR = (int*)alloc((size_t)(NG + 64) * 4);
    int*   cntR    = (int*)alloc((size_t)NG * 4);
    int*   rowlist = (int*)alloc((size_t)NG * 4);
    float* x1      = (float*)alloc((size_t)NG * NH * 4);   // alias: xsub
    float* x2      = (float*)alloc((size_t)NG * NH * 4);
    float* hbuf    = (float*)alloc((size_t)NG * NH * 4);   // alias: hf
    float* xpool   = (float*)alloc((size_t)S * KSEL * NH * 4);  // alias: ebuck (8MB of 16MB)
    float* xsub    = x1;
    float* hf      = hbuf;
    float* dinvN   = dinv;
    int*   cntN    = cnt_sub;
    int*   curN    = cur_sub;
    int*   curR    = cur_sub;
    int*   rowptrN = rowptr_s;
    int*   colN    = col_sub;
    int2*  ebuck   = (int2*)xpool;

    hipMemsetAsync(cnt_sub, 0, (size_t)NG * 4, stream);
    hipMemsetAsync(cntR, 0, (size_t)NG * 4, stream);

    // per-subgraph CSR
    k_count_sub<<<4096, 256, 0, stream>>>(sei, cnt_sub);
    k_scan_sub<<<S, 1024, 0, stream>>>(cnt_sub, rowptr_s, cur_sub, dinv);
    k_fill_sub<<<4096, 256, 0, stream>>>(sei, cur_sub, col_sub);

    // GCN1
    k_matmul<128, 128><<<dim3(NG / 64, 2), 256, 0, stream>>>(sub_x, W1, hbuf);
    k_agg128<<<8192, 256, 0, stream>>>((const float4*)hbuf, dinv, rowptr_s, col_sub, b1, (float4*)x1);
    // GCN2
    k_matmul<128, 128><<<dim3(NG / 64, 2), 256, 0, stream>>>(x1, W2, hbuf);
    k_agg128<<<8192, 256, 0, stream>>>((const float4*)hbuf, dinv, rowptr_s, col_sub, b2, (float4*)x2);
    // scorer GCN + top-k pooling
    k_score_h<<<NG / 4, 256, 0, stream>>>(x1, Wp, scoreh);
    k_score_agg<<<NG / 256, 256, 0, stream>>>(scoreh, dinv, rowptr_s, col_sub, bp, score);
    k_topk<<<S, 512, 0, stream>>>(score, perm, gate, posmap);
    k_deg2<<<(S * KSEL) / 256, 256, 0, stream>>>(perm, posmap, rowptr_s, col_sub, dinv2);
    k_xpool<<<(S * KSEL * 32) / 256, 256, 0, stream>>>((const float4*)x1, perm, gate, (float4*)xpool);
    k_emb<<<S, 1024, 0, stream>>>(xpool, subemb, 0);
    // pooled GCN (xsub aliases x1)
    k_matmul<128, 128><<<dim3((S * KSEL) / 64, 2), 256, 0, stream>>>(xpool, Wsc, hbuf);
    k_agg_pool<<<4096, 256, 0, stream>>>((const float4*)hbuf, dinv2, perm, posmap, rowptr_s, col_sub, bsc, (float4*)xsub);
    k_emb<<<S, 1024, 0, stream>>>(xsub, subemb, 1);
    // attention (degenerate)
    k_attn<<<S, 256, 0, stream>>>(subemb, Wqkv, bqkv, Wo, bo, att);

    // inverse-row CSR (orig -> rows), then non-atomic gather into gemb (no memset needed)
    k_countR<<<NG / 256, 256, 0, stream>>>(sorig, cntR);
    k_scanN_p1<<<64, 1024, 0, stream>>>(cntR, rowptrR, dinv, bsum);   // dinv = scratch here
    k_scanN_p2<<<1, 64, 0, stream>>>(bsum, boff);
    k_scanN_p3<<<64, 1024, 0, stream>>>(rowptrR, curR, boff, NG);
    k_fillR<<<NG / 256, 256, 0, stream>>>(sorig, curR, rowlist);
    k_gather<<<NG / 4, 384, 0, stream>>>((const float4*)x2, (const float4*)att,
                                         rowptrR, rowlist, (float4*)gemb);

    // global edge CSR: count + scan + bucketed fill (xpool/ebuck now dead-alias safe)
    hipMemsetAsync(cntN, 0, (size_t)NG * 4, stream);
    k_countN<<<EG / 256, 256, 0, stream>>>(gei, cntN);
    k_scanN_p1<<<64, 1024, 0, stream>>>(cntN, rowptrN, dinvN, bsum);  // real dinvN now
    k_scanN_p2<<<1, 64, 0, stream>>>(bsum, boff);
    k_scanN_p3<<<64, 1024, 0, stream>>>(rowptrN, curN, boff, EG);
    k_binit<<<2, 256, 0, stream>>>(rowptrN, bcur);
    k_bucket<<<EG / 256, 256, 0, stream>>>(gei, bcur, ebuck);
    k_fillB<<<NBUCK, 256, 0, stream>>>(ebuck, rowptrN, colN);

    // final GCN + log_softmax
    k_matmul<384, 64><<<dim3(NG / 64, 1), 256, 0, stream>>>(gemb, Wf, hf);
    k_final<<<NG / 16, 256, 0, stream>>>((const float4*)hf, dinvN, rowptrN, colN, bfb, (float4*)out0);

    (void)in_sizes; (void)n_in; (void)out_size; (void)ws_size;
}

// Round 7
// 838.746 us; speedup vs baseline: 1.2984x; 1.2984x over previous
//
#include <hip/hip_runtime.h>
#include <math.h>

#define S     64
#define NSUB  1024
#define ESUB  16384
#define NG    65536
#define EG    1048576
#define NH    128
#define KSEL  512

// ---------------- CSR build (per-subgraph) ----------------
__global__ void k_count_sub(const int* __restrict__ sei, int* __restrict__ cnt) {
    int e = blockIdx.x * 256 + threadIdx.x;          // < S*ESUB
    int s = e >> 14, el = e & (ESUB - 1);
    int dst = sei[s * 2 * ESUB + ESUB + el];
    atomicAdd(&cnt[s * NSUB + dst], 1);
}

__global__ __launch_bounds__(1024) void k_scan_sub(const int* __restrict__ cnt,
        int* __restrict__ rowptr, int* __restrict__ cur, float* __restrict__ dinv) {
    __shared__ int sh[1024];
    int s = blockIdx.x, t = threadIdx.x;
    int v = cnt[s * NSUB + t];
    sh[t] = v;
    __syncthreads();
    for (int off = 1; off < 1024; off <<= 1) {
        int add = (t >= off) ? sh[t - off] : 0;
        __syncthreads();
        sh[t] += add;
        __syncthreads();
    }
    int incl = sh[t];
    rowptr[s * (NSUB + 1) + t] = incl - v;
    cur[s * NSUB + t] = incl - v;
    dinv[s * NSUB + t] = rsqrtf((float)(v + 1));     // deg = indeg + 1 (self loop)
    if (t == 1023) rowptr[s * (NSUB + 1) + NSUB] = incl;
}

__global__ void k_fill_sub(const int* __restrict__ sei, int* __restrict__ cur,
                           int* __restrict__ col) {
    int e = blockIdx.x * 256 + threadIdx.x;
    int s = e >> 14, el = e & (ESUB - 1);
    int src = sei[s * 2 * ESUB + el];
    int dst = sei[s * 2 * ESUB + ESUB + el];
    int p = atomicAdd(&cur[s * NSUB + dst], 1);
    col[s * ESUB + p] = src;
}

// ---------------- tiled matmul: Y[M,NCOL] = X[M,KDIM] @ W[KDIM,NCOL] (all f32) --------
template<int KDIM, int NCOL>
__global__ __launch_bounds__(256) void k_matmul(const float* __restrict__ X,
        const float* __restrict__ W, float* __restrict__ Y) {
    __shared__ float As[16][72];
    __shared__ float Bs[16][72];
    int t = threadIdx.x;
    int row0 = blockIdx.x * 64;
    int col0 = blockIdx.y * 64;
    int tr = t >> 4, tc = t & 15;
    float acc[4][4] = {};
    for (int k0 = 0; k0 < KDIM; k0 += 16) {
        {   // stage A: 64 rows x 16 k
            int r = t >> 2, kq = t & 3;
            float4 v = *(const float4*)&X[(size_t)(row0 + r) * KDIM + k0 + kq * 4];
            As[kq * 4 + 0][r] = v.x; As[kq * 4 + 1][r] = v.y;
            As[kq * 4 + 2][r] = v.z; As[kq * 4 + 3][r] = v.w;
        }
        {   // stage B
            int k = t >> 4, cq = t & 15;
            float4 v = *(const float4*)&W[(size_t)(k0 + k) * NCOL + col0 + cq * 4];
            *(float4*)&Bs[k][cq * 4] = v;
        }
        __syncthreads();
        #pragma unroll
        for (int k = 0; k < 16; k++) {
            float a0 = As[k][tr * 4 + 0], a1 = As[k][tr * 4 + 1];
            float a2 = As[k][tr * 4 + 2], a3 = As[k][tr * 4 + 3];
            float b0 = Bs[k][tc * 4 + 0], b1 = Bs[k][tc * 4 + 1];
            float b2 = Bs[k][tc * 4 + 2], b3 = Bs[k][tc * 4 + 3];
            acc[0][0] += a0 * b0; acc[0][1] += a0 * b1; acc[0][2] += a0 * b2; acc[0][3] += a0 * b3;
            acc[1][0] += a1 * b0; acc[1][1] += a1 * b1; acc[1][2] += a1 * b2; acc[1][3] += a1 * b3;
            acc[2][0] += a2 * b0; acc[2][1] += a2 * b1; acc[2][2] += a2 * b2; acc[2][3] += a2 * b3;
            acc[3][0] += a3 * b0; acc[3][1] += a3 * b1; acc[3][2] += a3 * b2; acc[3][3] += a3 * b3;
        }
        __syncthreads();
    }
    #pragma unroll
    for (int i = 0; i < 4; i++) {
        float4 v = { acc[i][0], acc[i][1], acc[i][2], acc[i][3] };
        *(float4*)&Y[(size_t)(row0 + tr * 4 + i) * NCOL + col0 + tc * 4] = v;
    }
}

// ------- GCN aggregate (128 feats) + self + bias + relu; float4 + XCD swizzle --------
__global__ __launch_bounds__(256) void k_agg128(const float4* __restrict__ h,
        const float* __restrict__ dinv, const int* __restrict__ rowptr,
        const int* __restrict__ col, const float* __restrict__ bias,
        float4* __restrict__ out) {
    int b = blockIdx.x;
    int s = b & 63;                      // subgraph -> fixed XCD (b%8 == s%8)
    int chunk = b >> 6;
    int t = threadIdx.x;
    int nl = chunk * 8 + (t >> 5);
    int f4 = t & 31;
    const int* rp = rowptr + s * (NSUB + 1);
    int st = rp[nl], en = rp[nl + 1];
    const int* cl = col + s * ESUB;
    const float* dv = dinv + s * NSUB;
    float4 acc = {0.f, 0.f, 0.f, 0.f};
    for (int p = st; p < en; p++) {
        int src = cl[p];
        float d = dv[src];
        float4 hv = h[((size_t)(s * NSUB + src)) * 32 + f4];
        acc.x += hv.x * d; acc.y += hv.y * d; acc.z += hv.z * d; acc.w += hv.w * d;
    }
    size_t node = (size_t)s * NSUB + nl;
    float dn = dv[nl];
    float dn2 = dn * dn;
    float4 hs = h[node * 32 + f4];
    float4 bb = ((const float4*)bias)[f4];
    float4 r;
    r.x = fmaxf(acc.x * dn + hs.x * dn2 + bb.x, 0.f);
    r.y = fmaxf(acc.y * dn + hs.y * dn2 + bb.y, 0.f);
    r.z = fmaxf(acc.z * dn + hs.z * dn2 + bb.z, 0.f);
    r.w = fmaxf(acc.w * dn + hs.w * dn2 + bb.w, 0.f);
    out[node * 32 + f4] = r;
}

// ---------------- scorer ----------------
__global__ void k_score_h(const float* __restrict__ x1, const float* __restrict__ Wp,
                          float* __restrict__ sh) {
    int t = threadIdx.x;
    int n = blockIdx.x * 4 + (t >> 6);
    int l = t & 63;
    float p = x1[(size_t)n * NH + l] * Wp[l] + x1[(size_t)n * NH + 64 + l] * Wp[64 + l];
    for (int o = 32; o > 0; o >>= 1) p += __shfl_xor(p, o, 64);
    if (l == 0) sh[n] = p;
}

__global__ void k_score_agg(const float* __restrict__ sh, const float* __restrict__ dinv,
                            const int* __restrict__ rowptr, const int* __restrict__ col,
                            const float* __restrict__ bp, float* __restrict__ score) {
    int n = blockIdx.x * 256 + threadIdx.x;
    int s = n >> 10, nl = n & (NSUB - 1);
    const int* rp = rowptr + s * (NSUB + 1);
    const int* cl = col + s * ESUB;
    const float* dv = dinv + s * NSUB;
    int st = rp[nl], en = rp[nl + 1];
    float acc = 0.f;
    for (int p = st; p < en; p++) {
        int src = cl[p];
        acc += sh[s * NSUB + src] * dv[src];
    }
    float dn = dv[nl];
    score[n] = acc * dn + sh[n] * dn * dn + bp[0];
}

// ---------------- per-subgraph top-K (bitonic; set-invariant downstream) -----
__global__ __launch_bounds__(512) void k_topk(const float* __restrict__ score,
        int* __restrict__ perm, float* __restrict__ gate, int* __restrict__ posmap) {
    __shared__ float sv[1024];
    __shared__ int   si[1024];
    int s = blockIdx.x, t = threadIdx.x;
    for (int i = t; i < 1024; i += 512) {
        sv[i] = score[s * NSUB + i];
        si[i] = i;
        posmap[s * NSUB + i] = -1;
    }
    __syncthreads();
    for (int k = 2; k <= 1024; k <<= 1) {
        for (int j = k >> 1; j > 0; j >>= 1) {
            for (int b = t; b < 1024; b += 512) {
                int ixj = b ^ j;
                if (ixj > b) {
                    bool desc = ((b & k) == 0);
                    bool sw = desc ? (sv[b] < sv[ixj]) : (sv[b] > sv[ixj]);
                    if (sw) {
                        float tv = sv[b]; sv[b] = sv[ixj]; sv[ixj] = tv;
                        int ti = si[b]; si[b] = si[ixj]; si[ixj] = ti;
                    }
                }
            }
            __syncthreads();
        }
    }
    if (t < KSEL) {
        perm[s * KSEL + t] = si[t];
        gate[s * KSEL + t] = tanhf(sv[t]);
        posmap[s * NSUB + si[t]] = t;
    }
}

__global__ void k_deg2(const int* __restrict__ perm, const int* __restrict__ posmap,
                       const int* __restrict__ rowptr, const int* __restrict__ col,
                       float* __restrict__ dinv2) {
    int i = blockIdx.x * 256 + threadIdx.x;
    int s = i >> 9;
    int n = perm[i];
    const int* rp = rowptr + s * (NSUB + 1);
    const int* cl = col + s * ESUB;
    int st = rp[n], en = rp[n + 1];
    int cnt = 0;
    for (int p = st; p < en; p++) cnt += (posmap[s * NSUB + cl[p]] >= 0) ? 1 : 0;
    dinv2[i] = rsqrtf((float)(cnt + 1));
}

__global__ void k_xpool(const float4* __restrict__ x1, const int* __restrict__ perm,
                        const float* __restrict__ gate, float4* __restrict__ xpool) {
    int tid = blockIdx.x * 256 + threadIdx.x;
    int i = tid >> 5, f4 = tid & 31;
    int s = i >> 9;
    float g = gate[i];
    float4 v = x1[((size_t)(s * NSUB + perm[i])) * 32 + f4];
    v.x *= g; v.y *= g; v.z *= g; v.w *= g;
    xpool[tid] = v;
}

// max/mean over 512 rows -> [256] per subgraph; 4-sliced
__global__ __launch_bounds__(1024) void k_emb(const float* __restrict__ X,
        float* __restrict__ out, int addFlag) {
    __shared__ float red[4][256];
    int s = blockIdx.x, t = threadIdx.x;
    int sl = t >> 8, f = t & 255;
    const float* base = X + (size_t)s * KSEL * NH;
    float r;
    if (f < NH) {
        r = -INFINITY;
        for (int i = sl * 128; i < sl * 128 + 128; i++) r = fmaxf(r, base[i * NH + f]);
    } else {
        r = 0.f;
        for (int i = sl * 128; i < sl * 128 + 128; i++) r += base[i * NH + (f - NH)];
    }
    red[sl][f] = r;
    __syncthreads();
    if (sl == 0) {
        float a = red[0][f], b = red[1][f], c = red[2][f], d = red[3][f];
        float v = (f < NH) ? fmaxf(fmaxf(a, b), fmaxf(c, d)) : (a + b + c + d) * (1.f / KSEL);
        out[s * 256 + f] = addFlag ? out[s * 256 + f] + v : v;
    }
}

// pooled GCN aggregate; float4 + XCD swizzle
__global__ __launch_bounds__(256) void k_agg_pool(const float4* __restrict__ hp,
        const float* __restrict__ dinv2, const int* __restrict__ perm,
        const int* __restrict__ posmap, const int* __restrict__ rowptr,
        const int* __restrict__ col, const float* __restrict__ bsc,
        float4* __restrict__ xsub) {
    int b = blockIdx.x;
    int s = b & 63;
    int chunk = b >> 6;
    int t = threadIdx.x;
    int il = chunk * 8 + (t >> 5);
    int f4 = t & 31;
    int i = s * KSEL + il;
    int n = perm[i];
    const int* rp = rowptr + s * (NSUB + 1);
    const int* cl = col + s * ESUB;
    int st = rp[n], en = rp[n + 1];
    float4 acc = {0.f, 0.f, 0.f, 0.f};
    for (int p = st; p < en; p++) {
        int j = posmap[s * NSUB + cl[p]];
        if (j >= 0) {
            float d = dinv2[s * KSEL + j];
            float4 hv = hp[((size_t)(s * KSEL + j)) * 32 + f4];
            acc.x += hv.x * d; acc.y += hv.y * d; acc.z += hv.z * d; acc.w += hv.w * d;
        }
    }
    float dn = dinv2[i];
    float dn2 = dn * dn;
    float4 hs = hp[(size_t)i * 32 + f4];
    float4 bb = ((const float4*)bsc)[f4];
    float4 r;
    r.x = fmaxf(acc.x * dn + hs.x * dn2 + bb.x, 0.f);
    r.y = fmaxf(acc.y * dn + hs.y * dn2 + bb.y, 0.f);
    r.z = fmaxf(acc.z * dn + hs.z * dn2 + bb.z, 0.f);
    r.w = fmaxf(acc.w * dn + hs.w * dn2 + bb.w, 0.f);
    xsub[(size_t)i * 32 + f4] = r;
}

// attention degenerates (seq_len=1): att = (se@Wv + bv)@Wo + bo
__global__ void k_attn(const float* __restrict__ subemb, const float* __restrict__ Wqkv,
                       const float* __restrict__ bqkv, const float* __restrict__ Wo,
                       const float* __restrict__ bo, float* __restrict__ att) {
    __shared__ float se[256], t1[256];
    int s = blockIdx.x, t = threadIdx.x;
    se[t] = subemb[s * 256 + t];
    __syncthreads();
    float acc = bqkv[512 + t];
    for (int k = 0; k < 256; k++) acc += se[k] * Wqkv[(size_t)k * 768 + 512 + t];
    t1[t] = acc;
    __syncthreads();
    float a2 = bo[t];
    for (int k = 0; k < 256; k++) a2 += t1[k] * Wo[(size_t)k * 256 + t];
    att[s * 256 + t] = a2;
}

// ---------------- generic counting-scan helpers (64x1024 = NG entries) --------
__global__ void k_countR(const int* __restrict__ orig, int* __restrict__ cnt) {
    int r = blockIdx.x * 256 + threadIdx.x;          // < NG
    atomicAdd(&cnt[orig[r]], 1);
}

__global__ __launch_bounds__(1024) void k_scanN_p1(const int* __restrict__ cnt,
        int* __restrict__ rowptr, float* __restrict__ dinvN, int* __restrict__ bsum) {
    __shared__ int sh[1024];
    int b = blockIdx.x, t = threadIdx.x;
    int v = cnt[b * 1024 + t];
    sh[t] = v;
    __syncthreads();
    for (int off = 1; off < 1024; off <<= 1) {
        int add = (t >= off) ? sh[t - off] : 0;
        __syncthreads();
        sh[t] += add;
        __syncthreads();
    }
    int incl = sh[t];
    rowptr[b * 1024 + t] = incl - v;
    dinvN[b * 1024 + t] = rsqrtf((float)(v + 1));
    if (t == 1023) bsum[b] = incl;
}

__global__ void k_scanN_p2(const int* __restrict__ bsum, int* __restrict__ boff) {
    if (threadIdx.x == 0) {
        int run = 0;
        for (int i = 0; i < 64; i++) { boff[i] = run; run += bsum[i]; }
    }
}

__global__ __launch_bounds__(1024) void k_scanN_p3(int* __restrict__ rowptr,
        int* __restrict__ cur, const int* __restrict__ boff, int total) {
    int b = blockIdx.x, t = threadIdx.x;
    int idx = b * 1024 + t;
    int r = rowptr[idx] + boff[b];
    rowptr[idx] = r;
    cur[idx] = r;
    if (idx == 0) rowptr[NG] = total;
}

__global__ void k_fillR(const int* __restrict__ orig, int* __restrict__ cur,
                        int* __restrict__ rowlist) {
    int r = blockIdx.x * 256 + threadIdx.x;          // < NG
    int p = atomicAdd(&cur[orig[r]], 1);
    rowlist[p] = r;
}

// gather-based global_emb build: one gemb row written once, no atomics, no memset
__global__ __launch_bounds__(384) void k_gather(const float4* __restrict__ x2,
        const float4* __restrict__ att, const int* __restrict__ rowptrR,
        const int* __restrict__ rowlist, float4* __restrict__ gemb) {
    int t = threadIdx.x;
    int g = blockIdx.x * 4 + (t / 96);               // 4 nodes / block
    int lane = t % 96;                               // 96 float4 = 384 feats
    int st = rowptrR[g], en = rowptrR[g + 1];
    float4 acc = {0.f, 0.f, 0.f, 0.f};
    for (int p = st; p < en; p++) {
        int row = rowlist[p];
        float4 v = (lane < 32) ? x2[(size_t)row * 32 + lane]
                               : att[(size_t)(row >> 10) * 64 + (lane - 32)];
        acc.x += v.x; acc.y += v.y; acc.z += v.z; acc.w += v.w;
    }
    gemb[(size_t)g * 96 + lane] = acc;
}

// ---------------- global edge CSR: count + direct fill (65536 cursors) --------
__global__ void k_countN(const int* __restrict__ gei, int* __restrict__ cnt) {
    int e = blockIdx.x * 256 + threadIdx.x;
    atomicAdd(&cnt[gei[EG + e]], 1);
}

__global__ void k_fillN(const int* __restrict__ gei, int* __restrict__ cur,
                        int* __restrict__ col) {
    int e = blockIdx.x * 256 + threadIdx.x;
    int src = gei[e], dst = gei[EG + e];
    int p = atomicAdd(&cur[dst], 1);
    col[p] = src;
}

// final GCN aggregate + bias + log_softmax (64 classes = 16 float4 lanes)
__global__ __launch_bounds__(256) void k_final(const float4* __restrict__ hf,
        const float* __restrict__ dinvN, const int* __restrict__ rowptr,
        const int* __restrict__ col, const float* __restrict__ bfb,
        float4* __restrict__ out) {
    int t = threadIdx.x;
    int n = blockIdx.x * 16 + (t >> 4);
    int f4 = t & 15;
    int st = rowptr[n], en = rowptr[n + 1];
    float4 acc = {0.f, 0.f, 0.f, 0.f};
    for (int p = st; p < en; p++) {
        int src = col[p];
        float d = dinvN[src];
        float4 hv = hf[(size_t)src * 16 + f4];
        acc.x += hv.x * d; acc.y += hv.y * d; acc.z += hv.z * d; acc.w += hv.w * d;
    }
    float dn = dinvN[n];
    float dn2 = dn * dn;
    float4 hs = hf[(size_t)n * 16 + f4];
    float4 bb = ((const float4*)bfb)[f4];
    float4 x;
    x.x = acc.x * dn + hs.x * dn2 + bb.x;
    x.y = acc.y * dn + hs.y * dn2 + bb.y;
    x.z = acc.z * dn + hs.z * dn2 + bb.z;
    x.w = acc.w * dn + hs.w * dn2 + bb.w;
    float m = fmaxf(fmaxf(x.x, x.y), fmaxf(x.z, x.w));
    for (int o = 1; o < 16; o <<= 1) m = fmaxf(m, __shfl_xor(m, o, 64));
    float ssum = expf(x.x - m) + expf(x.y - m) + expf(x.z - m) + expf(x.w - m);
    for (int o = 1; o < 16; o <<= 1) ssum += __shfl_xor(ssum, o, 64);
    float lz = m + logf(ssum);
    float4 r = { x.x - lz, x.y - lz, x.z - lz, x.w - lz };
    out[(size_t)n * 16 + f4] = r;
}

// ---------------- host ----------------
extern "C" void kernel_launch(void* const* d_in, const int* in_sizes, int n_in,
                              void* d_out, int out_size, void* d_ws, size_t ws_size,
                              hipStream_t stream) {
    const float* sub_x = (const float*)d_in[0];
    const int*   sei   = (const int*)d_in[1];
    const int*   sorig = (const int*)d_in[2];
    const int*   gei   = (const int*)d_in[3];
    const float *W1 = (const float*)d_in[4],  *b1  = (const float*)d_in[5];
    const float *W2 = (const float*)d_in[6],  *b2  = (const float*)d_in[7];
    const float *Wp = (const float*)d_in[8],  *bp  = (const float*)d_in[9];
    const float *Wsc = (const float*)d_in[10], *bsc = (const float*)d_in[11];
    const float *Wqkv = (const float*)d_in[12], *bqkv = (const float*)d_in[13];
    const float *Wo = (const float*)d_in[14], *bo  = (const float*)d_in[15];
    const float *Wf = (const float*)d_in[16], *bfb = (const float*)d_in[17];

    float* out0 = (float*)d_out;                      // log-softmax [NG,64]
    float* gemb = (float*)d_out + (size_t)NG * 64;    // global_emb [NG,384] in-place

    char* w = (char*)d_ws;
    size_t off = 0;
    auto alloc = [&](size_t nbytes) -> void* {
        off = (off + 255) & ~(size_t)255;
        void* p = w + off;
        off += nbytes;
        return p;
    };
    int*   bsum    = (int*)alloc(64 * 4);
    int*   boff    = (int*)alloc(64 * 4);
    float* dinv    = (float*)alloc((size_t)NG * 4);        // subgraph dinv; later dinvN + scan scratch
    float* scoreh  = (float*)alloc((size_t)NG * 4);
    float* score   = (float*)alloc((size_t)NG * 4);
    float* gate    = (float*)alloc((size_t)S * KSEL * 4);
    float* dinv2   = (float*)alloc((size_t)S * KSEL * 4);
    float* subemb  = (float*)alloc((size_t)S * 256 * 4);
    float* att     = (float*)alloc((size_t)S * 256 * 4);
    int*   perm    = (int*)alloc((size_t)S * KSEL * 4);
    int*   posmap  = (int*)alloc((size_t)NG * 4);
    int*   cnt_sub = (int*)alloc((size_t)NG * 4);          // alias: cntN
    int*   cur_sub = (int*)alloc((size_t)NG * 4);          // alias: curN/curR
    int*   rowptr_s= (int*)alloc((size_t)(NG + 64) * 4);   // alias: rowptrN
    int*   col_sub = (int*)alloc((size_t)EG * 4);          // alias: colN
    int*   rowptrR = (int*)alloc((size_t)(NG + 64) * 4);
    int*   cntR    = (int*)alloc((size_t)NG * 4);
    int*   rowlist = (int*)alloc((size_t)NG * 4);
    float* x1      = (float*)alloc((size_t)NG * NH * 4);   // alias: xsub
    float* x2      = (float*)alloc((size_t)NG * NH * 4);
    float* hbuf    = (float*)alloc((size_t)NG * NH * 4);   // alias: hf
    float* xpool   = (float*)alloc((size_t)S * KSEL * NH * 4);
    float* xsub    = x1;
    float* hf      = hbuf;
    float* dinvN   = dinv;
    int*   cntN    = cnt_sub;
    int*   curN    = cur_sub;
    int*   curR    = cur_sub;
    int*   rowptrN = rowptr_s;
    int*   colN    = col_sub;

    hipMemsetAsync(cnt_sub, 0, (size_t)NG * 4, stream);
    hipMemsetAsync(cntR, 0, (size_t)NG * 4, stream);

    // per-subgraph CSR
    k_count_sub<<<4096, 256, 0, stream>>>(sei, cnt_sub);
    k_scan_sub<<<S, 1024, 0, stream>>>(cnt_sub, rowptr_s, cur_sub, dinv);
    k_fill_sub<<<4096, 256, 0, stream>>>(sei, cur_sub, col_sub);

    // GCN1
    k_matmul<128, 128><<<dim3(NG / 64, 2), 256, 0, stream>>>(sub_x, W1, hbuf);
    k_agg128<<<8192, 256, 0, stream>>>((const float4*)hbuf, dinv, rowptr_s, col_sub, b1, (float4*)x1);
    // GCN2
    k_matmul<128, 128><<<dim3(NG / 64, 2), 256, 0, stream>>>(x1, W2, hbuf);
    k_agg128<<<8192, 256, 0, stream>>>((const float4*)hbuf, dinv, rowptr_s, col_sub, b2, (float4*)x2);
    // scorer GCN + top-k pooling
    k_score_h<<<NG / 4, 256, 0, stream>>>(x1, Wp, scoreh);
    k_score_agg<<<NG / 256, 256, 0, stream>>>(scoreh, dinv, rowptr_s, col_sub, bp, score);
    k_topk<<<S, 512, 0, stream>>>(score, perm, gate, posmap);
    k_deg2<<<(S * KSEL) / 256, 256, 0, stream>>>(perm, posmap, rowptr_s, col_sub, dinv2);
    k_xpool<<<(S * KSEL * 32) / 256, 256, 0, stream>>>((const float4*)x1, perm, gate, (float4*)xpool);
    k_emb<<<S, 1024, 0, stream>>>(xpool, subemb, 0);
    // pooled GCN (xsub aliases x1)
    k_matmul<128, 128><<<dim3((S * KSEL) / 64, 2), 256, 0, stream>>>(xpool, Wsc, hbuf);
    k_agg_pool<<<4096, 256, 0, stream>>>((const float4*)hbuf, dinv2, perm, posmap, rowptr_s, col_sub, bsc, (float4*)xsub);
    k_emb<<<S, 1024, 0, stream>>>(xsub, subemb, 1);
    // attention (degenerate)
    k_attn<<<S, 256, 0, stream>>>(subemb, Wqkv, bqkv, Wo, bo, att);

    // inverse-row CSR (orig -> rows), then non-atomic gather into gemb (no memset needed)
    k_countR<<<NG / 256, 256, 0, stream>>>(sorig, cntR);
    k_scanN_p1<<<64, 1024, 0, stream>>>(cntR, rowptrR, dinv, bsum);   // dinv = scratch here
    k_scanN_p2<<<1, 64, 0, stream>>>(bsum, boff);
    k_scanN_p3<<<64, 1024, 0, stream>>>(rowptrR, curR, boff, NG);
    k_fillR<<<NG / 256, 256, 0, stream>>>(sorig, curR, rowlist);
    k_gather<<<NG / 4, 384, 0, stream>>>((const float4*)x2, (const float4*)att,
                                         rowptrR, rowlist, (float4*)gemb);

    // global edge CSR: count + scan + direct fill (65536 cursors; low contention)
    hipMemsetAsync(cntN, 0, (size_t)NG * 4, stream);
    k_countN<<<EG / 256, 256, 0, stream>>>(gei, cntN);
    k_scanN_p1<<<64, 1024, 0, stream>>>(cntN, rowptrN, dinvN, bsum);  // real dinvN now
    k_scanN_p2<<<1, 64, 0, stream>>>(bsum, boff);
    k_scanN_p3<<<64, 1024, 0, stream>>>(rowptrN, curN, boff, EG);
    k_fillN<<<EG / 256, 256, 0, stream>>>(gei, curN, colN);

    // final GCN + log_softmax
    k_matmul<384, 64><<<dim3(NG / 64, 1), 256, 0, stream>>>(gemb, Wf, hf);
    k_final<<<NG / 16, 256, 0, stream>>>((const float4*)hf, dinvN, rowptrN, colN, bfb, (float4*)out0);

    (void)in_sizes; (void)n_in; (void)out_size; (void)ws_size;
}